// Round 9
// baseline (1605.573 us; speedup 1.0000x reference)
//
#include <hip/hip_runtime.h>

// LSTMPredictor: B=1024, T=512, IN=19, H=128, OUT=7 (fp32 in/out)
// L1: R3-proven kernel verbatim (R=4, 256 blocks, default occupancy).
// L2: 128 blocks x 512 thr, waves_per_eu(2,2) (256-VGPR budget, proven R7),
//     TWO independent R=4 recurrences per block (rows 8b..+3 / 8b+4..+7) ->
//     in-wave ILP: chain A's latency hides under chain B's instructions.
//     Weights pinned in VGPR; bias as f32x4 locals; Wlin read from LDS.
// D-layout row-duplication invariant (R3-proven): A-frag rows dup mod 4 ->
// acc_g[r] at every lane holds D_g[r][col]; lane picks its own reg (sel4).

typedef _Float16 half8 __attribute__((ext_vector_type(8)));
typedef float f32x4 __attribute__((ext_vector_type(4)));

#define MFMA16(a, b, c) __builtin_amdgcn_mfma_f32_16x16x32_f16((a), (b), (c), 0, 0, 0)
#define BARRIER() asm volatile("s_waitcnt lgkmcnt(0)\ns_barrier" ::: "memory")

__device__ __forceinline__ void pin(half8& v) { asm volatile("" : "+v"(v)); }

__device__ __forceinline__ float sigf(float x) {
  return __builtin_amdgcn_rcpf(1.f + __expf(-x));   // NaN-free at +/-inf
}
__device__ __forceinline__ float tanhf_(float x) {
  return 1.f - 2.f * __builtin_amdgcn_rcpf(1.f + __expf(2.f * x));  // NaN-free
}
// acc_g[r] == D_g[r][lc] at every lane (duplication invariant) -> pick reg lg.
__device__ __forceinline__ float sel4(const f32x4 a, const int lg) {
  const float v01 = (lg & 1) ? a[1] : a[0];
  const float v23 = (lg & 1) ? a[3] : a[2];
  return (lg & 2) ? v23 : v01;
}

// ---------------- Layer 1 (R3-proven, verbatim) ----------------
__global__ __launch_bounds__(512) void lstm_layer1_kernel(
    const float* __restrict__ x,        // [1024,512,19]
    const float* __restrict__ Wih,      // [512,19]
    const float* __restrict__ Whh,      // [512,128]
    const float* __restrict__ bih, const float* __restrict__ bhh,
    _Float16* __restrict__ h1g)         // [512][1024][128] fp16 (T-major)
{
  __shared__ _Float16 xls[512][12][8];  // 98,304 B: fp16 x A-frags (k padded to 24)
  __shared__ _Float16 hbuf[2][64][8];   // 2 KiB
  const int tid = threadIdx.x, bid = blockIdx.x;
  const int wv = tid >> 6, lane = tid & 63;
  const int lg = lane >> 4, lc = lane & 15;
  const int col = wv * 16 + lc;
  const int off0 = lg * 32 + (lc & 3) * 8;
  const int woff = ((wv * 2 + (lc >> 3)) * 4 + lg) * 8 + (lc & 7);

  half8 wih_f[4], whh_f[4][4];
  float bias[4];
#pragma unroll
  for (int g = 0; g < 4; ++g) {
    const int n = g * 128 + col;
    bias[g] = bih[n] + bhh[n];
    half8 f;
#pragma unroll
    for (int j = 0; j < 8; ++j) {
      const int k = lg * 8 + j;
      f[j] = (_Float16)((k < 19) ? Wih[n * 19 + k] : 0.f);
    }
    wih_f[g] = f;
#pragma unroll
    for (int kk = 0; kk < 4; ++kk) {
      const float* p = Whh + n * 128 + kk * 32 + lg * 8;
      half8 f2;
#pragma unroll
      for (int j = 0; j < 8; ++j) f2[j] = (_Float16)p[j];
      whh_f[g][kk] = f2;
    }
  }

  for (int i2 = tid; i2 < 512 * 96; i2 += 512) {
    const int t = i2 / 96, r = i2 - t * 96;
    const int cc = r >> 5, rr = (r >> 3) & 3, j = r & 7;
    const int k = cc * 8 + j;
    float v = 0.f;
    if (k < 19) v = x[((size_t)(bid * 4 + rr) * 512 + t) * 19 + k];
    xls[t][cc * 4 + rr][j] = (_Float16)v;
  }
  for (int i = tid; i < 1024; i += 512) ((_Float16*)hbuf)[i] = (_Float16)0.f;
  __syncthreads();

  float c = 0.f;
  _Float16* h1p = h1g + (size_t)(bid * 4 + lg) * 128 + col;
  const _Float16* xb = &xls[0][0][0] + off0;
  _Float16* hb0p = &hbuf[0][0][0];
  const f32x4 fz = {0.f, 0.f, 0.f, 0.f};
  const bool xv = (lg < 3);

#define L1_STEP(T, RD, WR)                                                    \
  {                                                                           \
    const _Float16* rd = (RD) + off0;                                         \
    const half8 hb0 = *(const half8*)(rd);                                    \
    const half8 hb1 = *(const half8*)(rd + 128);                              \
    const half8 hb2 = *(const half8*)(rd + 256);                              \
    const half8 hb3 = *(const half8*)(rd + 384);                              \
    half8 ax = {};                                                            \
    if (xv) ax = *(const half8*)(xb + (T) * 96);                              \
    f32x4 a0 = MFMA16(ax, wih_f[0], fz);                                      \
    f32x4 a1 = MFMA16(ax, wih_f[1], fz);                                      \
    f32x4 a2 = MFMA16(ax, wih_f[2], fz);                                      \
    f32x4 a3 = MFMA16(ax, wih_f[3], fz);                                      \
    a0 = MFMA16(hb0, whh_f[0][0], a0); a1 = MFMA16(hb0, whh_f[1][0], a1);     \
    a2 = MFMA16(hb0, whh_f[2][0], a2); a3 = MFMA16(hb0, whh_f[3][0], a3);     \
    a0 = MFMA16(hb1, whh_f[0][1], a0); a1 = MFMA16(hb1, whh_f[1][1], a1);     \
    a2 = MFMA16(hb1, whh_f[2][1], a2); a3 = MFMA16(hb1, whh_f[3][1], a3);     \
    a0 = MFMA16(hb2, whh_f[0][2], a0); a1 = MFMA16(hb2, whh_f[1][2], a1);     \
    a2 = MFMA16(hb2, whh_f[2][2], a2); a3 = MFMA16(hb2, whh_f[3][2], a3);     \
    a0 = MFMA16(hb3, whh_f[0][3], a0); a1 = MFMA16(hb3, whh_f[1][3], a1);     \
    a2 = MFMA16(hb3, whh_f[2][3], a2); a3 = MFMA16(hb3, whh_f[3][3], a3);     \
    const float gi = sel4(a0, lg) + bias[0];                                  \
    const float gf = sel4(a1, lg) + bias[1];                                  \
    const float gg = sel4(a2, lg) + bias[2];                                  \
    const float go = sel4(a3, lg) + bias[3];                                  \
    const float I = sigf(gi), F = sigf(gf), G = tanhf_(gg), O = sigf(go);     \
    c = F * c + I * G;                                                        \
    const float h = O * tanhf_(c);                                            \
    const _Float16 h16 = (_Float16)h;                                         \
    (WR)[woff] = h16;                                                         \
    h1p[(size_t)(T) * 131072] = h16;                                          \
    BARRIER();                                                                \
  }

#pragma unroll 1
  for (int t = 0; t < 512; t += 2) {
    L1_STEP(t, hb0p + 512, hb0p);
    L1_STEP(t + 1, hb0p, hb0p + 512);
  }
#undef L1_STEP
}

// ------- Layer 2 + Linear: 128 blocks, 2 chains/block, 2 waves/EU -------
__global__ __attribute__((amdgpu_waves_per_eu(2, 2))) __launch_bounds__(512)
void lstm_layer2_kernel(
    const _Float16* __restrict__ h1g,   // [512][1024][128]
    const float* __restrict__ Wih,      // [512,128]
    const float* __restrict__ Whh,      // [512,128]
    const float* __restrict__ bih, const float* __restrict__ bhh,
    const float* __restrict__ Wlin,     // [7,128]
    const float* __restrict__ blin,     // [7]
    float* __restrict__ out)            // [1024, 3584]
{
  __shared__ _Float16 hbuf[2][2][512];  // [buf][chain][frag layout] 4 KiB
  __shared__ _Float16 wlls[16][136];    // Wlin staged (pad 136 -> 2-way banks)
  const int tid = threadIdx.x, bid = blockIdx.x;
  const int wv = tid >> 6, lane = tid & 63;
  const int lg = lane >> 4, lc = lane & 15;
  const int col = wv * 16 + lc;
  const int off0 = lg * 32 + (lc & 3) * 8;
  const int woff = ((col >> 3) * 4 + lg) * 8 + (col & 7);

  half8 wi_f[4][4], wh_f[4][4];
  float bias_s[4];
#pragma unroll
  for (int g = 0; g < 4; ++g) {
    const int n = g * 128 + col;
    bias_s[g] = bih[n] + bhh[n];
#pragma unroll
    for (int kk = 0; kk < 4; ++kk) {
      const float* pi = Wih + n * 128 + kk * 32 + lg * 8;
      const float* ph = Whh + n * 128 + kk * 32 + lg * 8;
      half8 fi, fh;
#pragma unroll
      for (int j = 0; j < 8; ++j) { fi[j] = (_Float16)pi[j]; fh[j] = (_Float16)ph[j]; }
      wi_f[g][kk] = fi;
      wh_f[g][kk] = fh;
    }
    pin(wi_f[g][0]); pin(wi_f[g][1]); pin(wi_f[g][2]); pin(wi_f[g][3]);
    pin(wh_f[g][0]); pin(wh_f[g][1]); pin(wh_f[g][2]); pin(wh_f[g][3]);
  }
  // bias as named f32x4 locals (NO braced literals inside macro args)
  const f32x4 bV0 = {bias_s[0], bias_s[0], bias_s[0], bias_s[0]};
  const f32x4 bV1 = {bias_s[1], bias_s[1], bias_s[1], bias_s[1]};
  const f32x4 bV2 = {bias_s[2], bias_s[2], bias_s[2], bias_s[2]};
  const f32x4 bV3 = {bias_s[3], bias_s[3], bias_s[3], bias_s[3]};

  const bool yduty = (wv < 2);          // wave 0: chain A's y, wave 1: chain B's y
  const bool yv = (lc < 7);
  const float ybias = (yduty && yv) ? blin[lc] : 0.f;

  for (int i = tid; i < 16 * 128; i += 512)
    wlls[i >> 7][i & 127] = (_Float16)((i < 7 * 128) ? Wlin[i] : 0.f);
  for (int i = tid; i < 2048; i += 512) ((_Float16*)hbuf)[i] = (_Float16)0.f;
  __syncthreads();

  float cA = 0.f, cB = 0.f;
  // chain A rows: bid*8 + 0..3 ; chain B rows: bid*8 + 4..7
  const _Float16* h1pA = h1g + (size_t)(bid * 8 + (lc & 3)) * 128 + lg * 8;
  const _Float16* h1pB = h1pA + 512;
  const _Float16* wlp = &wlls[lc][0] + lg * 8;

  half8 cA0 = *(const half8*)(h1pA +  0), cA1 = *(const half8*)(h1pA + 32);
  half8 cA2 = *(const half8*)(h1pA + 64), cA3 = *(const half8*)(h1pA + 96);
  half8 cB0 = *(const half8*)(h1pB +  0), cB1 = *(const half8*)(h1pB + 32);
  half8 cB2 = *(const half8*)(h1pB + 64), cB3 = *(const half8*)(h1pB + 96);
  half8 nA0 = {}, nA1 = {}, nA2 = {}, nA3 = {};
  half8 nB0 = {}, nB1 = {}, nB2 = {}, nB3 = {};

#define L2_STEP(T, IA0, IA1, IA2, IA3, IB0, IB1, IB2, IB3,                    \
                   JA0, JA1, JA2, JA3, JB0, JB1, JB2, JB3)                    \
  {                                                                           \
    const _Float16* rdA = &hbuf[((T) & 1) ^ 1][0][0] + off0;                  \
    const _Float16* rdB = &hbuf[((T) & 1) ^ 1][1][0] + off0;                  \
    const half8 hA0 = *(const half8*)(rdA);                                   \
    const half8 hA1 = *(const half8*)(rdA + 128);                             \
    const half8 hA2 = *(const half8*)(rdA + 256);                             \
    const half8 hA3 = *(const half8*)(rdA + 384);                             \
    const half8 hB0 = *(const half8*)(rdB);                                   \
    const half8 hB1 = *(const half8*)(rdB + 128);                             \
    const half8 hB2 = *(const half8*)(rdB + 256);                             \
    const half8 hB3 = *(const half8*)(rdB + 384);                             \
    const size_t tn = (size_t)((T) + 1 < 512 ? (T) + 1 : 511) * 131072;       \
    JA0 = *(const half8*)(h1pA + tn);                                         \
    JA1 = *(const half8*)(h1pA + tn + 32);                                    \
    JA2 = *(const half8*)(h1pA + tn + 64);                                    \
    JA3 = *(const half8*)(h1pA + tn + 96);                                    \
    JB0 = *(const half8*)(h1pB + tn);                                         \
    JB1 = *(const half8*)(h1pB + tn + 32);                                    \
    JB2 = *(const half8*)(h1pB + tn + 64);                                    \
    JB3 = *(const half8*)(h1pB + tn + 96);                                    \
    f32x4 aA0 = MFMA16(IA0, wi_f[0][0], bV0);                                 \
    f32x4 aB0 = MFMA16(IB0, wi_f[0][0], bV0);                                 \
    f32x4 aA1 = MFMA16(IA0, wi_f[1][0], bV1);                                 \
    f32x4 aB1 = MFMA16(IB0, wi_f[1][0], bV1);                                 \
    f32x4 aA2 = MFMA16(IA0, wi_f[2][0], bV2);                                 \
    f32x4 aB2 = MFMA16(IB0, wi_f[2][0], bV2);                                 \
    f32x4 aA3 = MFMA16(IA0, wi_f[3][0], bV3);                                 \
    f32x4 aB3 = MFMA16(IB0, wi_f[3][0], bV3);                                 \
    aA0 = MFMA16(IA1, wi_f[0][1], aA0); aB0 = MFMA16(IB1, wi_f[0][1], aB0);   \
    aA1 = MFMA16(IA1, wi_f[1][1], aA1); aB1 = MFMA16(IB1, wi_f[1][1], aB1);   \
    aA2 = MFMA16(IA1, wi_f[2][1], aA2); aB2 = MFMA16(IB1, wi_f[2][1], aB2);   \
    aA3 = MFMA16(IA1, wi_f[3][1], aA3); aB3 = MFMA16(IB1, wi_f[3][1], aB3);   \
    aA0 = MFMA16(IA2, wi_f[0][2], aA0); aB0 = MFMA16(IB2, wi_f[0][2], aB0);   \
    aA1 = MFMA16(IA2, wi_f[1][2], aA1); aB1 = MFMA16(IB2, wi_f[1][2], aB1);   \
    aA2 = MFMA16(IA2, wi_f[2][2], aA2); aB2 = MFMA16(IB2, wi_f[2][2], aB2);   \
    aA3 = MFMA16(IA2, wi_f[3][2], aA3); aB3 = MFMA16(IB2, wi_f[3][2], aB3);   \
    aA0 = MFMA16(IA3, wi_f[0][3], aA0); aB0 = MFMA16(IB3, wi_f[0][3], aB0);   \
    aA1 = MFMA16(IA3, wi_f[1][3], aA1); aB1 = MFMA16(IB3, wi_f[1][3], aB1);   \
    aA2 = MFMA16(IA3, wi_f[2][3], aA2); aB2 = MFMA16(IB3, wi_f[2][3], aB2);   \
    aA3 = MFMA16(IA3, wi_f[3][3], aA3); aB3 = MFMA16(IB3, wi_f[3][3], aB3);   \
    aA0 = MFMA16(hA0, wh_f[0][0], aA0); aB0 = MFMA16(hB0, wh_f[0][0], aB0);   \
    aA1 = MFMA16(hA0, wh_f[1][0], aA1); aB1 = MFMA16(hB0, wh_f[1][0], aB1);   \
    aA2 = MFMA16(hA0, wh_f[2][0], aA2); aB2 = MFMA16(hB0, wh_f[2][0], aB2);   \
    aA3 = MFMA16(hA0, wh_f[3][0], aA3); aB3 = MFMA16(hB0, wh_f[3][0], aB3);   \
    aA0 = MFMA16(hA1, wh_f[0][1], aA0); aB0 = MFMA16(hB1, wh_f[0][1], aB0);   \
    aA1 = MFMA16(hA1, wh_f[1][1], aA1); aB1 = MFMA16(hB1, wh_f[1][1], aB1);   \
    aA2 = MFMA16(hA1, wh_f[2][1], aA2); aB2 = MFMA16(hB1, wh_f[2][1], aB2);   \
    aA3 = MFMA16(hA1, wh_f[3][1], aA3); aB3 = MFMA16(hB1, wh_f[3][1], aB3);   \
    aA0 = MFMA16(hA2, wh_f[0][2], aA0); aB0 = MFMA16(hB2, wh_f[0][2], aB0);   \
    aA1 = MFMA16(hA2, wh_f[1][2], aA1); aB1 = MFMA16(hB2, wh_f[1][2], aB1);   \
    aA2 = MFMA16(hA2, wh_f[2][2], aA2); aB2 = MFMA16(hB2, wh_f[2][2], aB2);   \
    aA3 = MFMA16(hA2, wh_f[3][2], aA3); aB3 = MFMA16(hB2, wh_f[3][2], aB3);   \
    aA0 = MFMA16(hA3, wh_f[0][3], aA0); aB0 = MFMA16(hB3, wh_f[0][3], aB0);   \
    aA1 = MFMA16(hA3, wh_f[1][3], aA1); aB1 = MFMA16(hB3, wh_f[1][3], aB1);   \
    aA2 = MFMA16(hA3, wh_f[2][3], aA2); aB2 = MFMA16(hB3, wh_f[2][3], aB2);   \
    aA3 = MFMA16(hA3, wh_f[3][3], aA3); aB3 = MFMA16(hB3, wh_f[3][3], aB3);   \
    if (yduty && (T) > 0) {                                                   \
      const half8 g0 = (wv == 0) ? hA0 : hB0;                                 \
      const half8 g1 = (wv == 0) ? hA1 : hB1;                                 \
      const half8 g2 = (wv == 0) ? hA2 : hB2;                                 \
      const half8 g3 = (wv == 0) ? hA3 : hB3;                                 \
      const half8 w0 = *(const half8*)(wlp);                                  \
      const half8 w1 = *(const half8*)(wlp + 32);                             \
      const half8 w2 = *(const half8*)(wlp + 64);                             \
      const half8 w3 = *(const half8*)(wlp + 96);                             \
      f32x4 ya = {ybias, ybias, ybias, ybias};                                \
      ya = MFMA16(g0, w0, ya);                                                \
      ya = MFMA16(g1, w1, ya);                                                \
      ya = MFMA16(g2, w2, ya);                                                \
      ya = MFMA16(g3, w3, ya);                                                \
      if (lg == 0 && yv) {                                                    \
        _Pragma("unroll")                                                     \
        for (int j = 0; j < 4; ++j)                                           \
          out[(size_t)(bid * 8 + wv * 4 + j) * 3584 + (size_t)((T)-1) * 7 + lc] = ya[j]; \
      }                                                                       \
    }                                                                         \
    {                                                                         \
      const float gi = sel4(aA0, lg), gf = sel4(aA1, lg);                     \
      const float gg = sel4(aA2, lg), go = sel4(aA3, lg);                     \
      const float I = sigf(gi), F = sigf(gf), G = tanhf_(gg), O = sigf(go);   \
      cA = F * cA + I * G;                                                    \
      hbuf[(T) & 1][0][woff] = (_Float16)(O * tanhf_(cA));                    \
    }                                                                         \
    {                                                                         \
      const float gi = sel4(aB0, lg), gf = sel4(aB1, lg);                     \
      const float gg = sel4(aB2, lg), go = sel4(aB3, lg);                     \
      const float I = sigf(gi), F = sigf(gf), G = tanhf_(gg), O = sigf(go);   \
      cB = F * cB + I * G;                                                    \
      hbuf[(T) & 1][1][woff] = (_Float16)(O * tanhf_(cB));                    \
    }                                                                         \
    BARRIER();                                                                \
  }

#pragma unroll 1
  for (int t = 0; t < 512; t += 2) {
    L2_STEP(t,     cA0, cA1, cA2, cA3, cB0, cB1, cB2, cB3,
                   nA0, nA1, nA2, nA3, nB0, nB1, nB2, nB3);
    L2_STEP(t + 1, nA0, nA1, nA2, nA3, nB0, nB1, nB2, nB3,
                   cA0, cA1, cA2, cA3, cB0, cB1, cB2, cB3);
  }
#undef L2_STEP

  // final y(511) from h2(511) in hbuf[1]
  if (yduty) {
    const _Float16* rd = &hbuf[1][wv][0] + off0;
    const half8 g0 = *(const half8*)(rd);
    const half8 g1 = *(const half8*)(rd + 128);
    const half8 g2 = *(const half8*)(rd + 256);
    const half8 g3 = *(const half8*)(rd + 384);
    const half8 w0 = *(const half8*)(wlp);
    const half8 w1 = *(const half8*)(wlp + 32);
    const half8 w2 = *(const half8*)(wlp + 64);
    const half8 w3 = *(const half8*)(wlp + 96);
    f32x4 ya = {ybias, ybias, ybias, ybias};
    ya = MFMA16(g0, w0, ya);
    ya = MFMA16(g1, w1, ya);
    ya = MFMA16(g2, w2, ya);
    ya = MFMA16(g3, w3, ya);
    if (lg == 0 && yv) {
#pragma unroll
      for (int j = 0; j < 4; ++j)
        out[(size_t)(bid * 8 + wv * 4 + j) * 3584 + (size_t)511 * 7 + lc] = ya[j];
    }
  }
}

extern "C" void kernel_launch(void* const* d_in, const int* in_sizes, int n_in,
                              void* d_out, int out_size, void* d_ws, size_t ws_size,
                              hipStream_t stream) {
  (void)in_sizes; (void)n_in; (void)out_size; (void)ws_size;
  const float* x     = (const float*)d_in[0];
  const float* W_ih1 = (const float*)d_in[1];
  const float* W_hh1 = (const float*)d_in[2];
  const float* b_ih1 = (const float*)d_in[3];
  const float* b_hh1 = (const float*)d_in[4];
  const float* W_ih2 = (const float*)d_in[5];
  const float* W_hh2 = (const float*)d_in[6];
  const float* b_ih2 = (const float*)d_in[7];
  const float* b_hh2 = (const float*)d_in[8];
  const float* W_lin = (const float*)d_in[9];
  const float* b_lin = (const float*)d_in[10];
  float* out = (float*)d_out;
  _Float16* h1g = (_Float16*)d_ws;   // [512][1024][128] fp16 = 134,217,728 bytes

  lstm_layer1_kernel<<<256, 512, 0, stream>>>(x, W_ih1, W_hh1, b_ih1, b_hh1, h1g);
  lstm_layer2_kernel<<<128, 512, 0, stream>>>(h1g, W_ih2, W_hh2, b_ih2, b_hh2,
                                              W_lin, b_lin, out);
}

// Round 10
// 1268.741 us; speedup vs baseline: 1.2655x; 1.2655x over previous
//
#include <hip/hip_runtime.h>

// LSTMPredictor: B=1024, T=512, IN=19, H=128, OUT=7 (fp32 in/out)
// L1: R3-proven kernel verbatim.
// L2 split: (a) pre-GEMM  P(t)=bias2+h1(t)@Wih2^T  (feed-forward, fp16 to ws)
//           (b) recurrence: only wh2 in regs (64 VGPR -> spill-free at the
//               observed 128-VGPR budget); P streamed+prefetched from HBM.
// Chunked by ws_size (Tc in {512,256,128,64}); R7-L2 fallback if ws too small.
// D-layout row-dup invariant (R3): A-frag rows dup mod 4 -> acc_g[r] at every
// lane holds D_g[r][col]; lane (lg,lc) selects its own reg lg (sel4).

typedef _Float16 half8 __attribute__((ext_vector_type(8)));
typedef _Float16 half4 __attribute__((ext_vector_type(4)));
typedef float f32x4 __attribute__((ext_vector_type(4)));

#define MFMA16(a, b, c) __builtin_amdgcn_mfma_f32_16x16x32_f16((a), (b), (c), 0, 0, 0)
#define BARRIER() asm volatile("s_waitcnt lgkmcnt(0)\ns_barrier" ::: "memory")

__device__ __forceinline__ void pin(half8& v) { asm volatile("" : "+v"(v)); }
__device__ __forceinline__ void pinf(f32x4& v) { asm volatile("" : "+v"(v)); }

__device__ __forceinline__ float sigf(float x) {
  return __builtin_amdgcn_rcpf(1.f + __expf(-x));   // NaN-free at +/-inf
}
__device__ __forceinline__ float tanhf_(float x) {
  return 1.f - 2.f * __builtin_amdgcn_rcpf(1.f + __expf(2.f * x));  // NaN-free
}
__device__ __forceinline__ float sel4(const f32x4 a, const int lg) {
  const float v01 = (lg & 1) ? a[1] : a[0];
  const float v23 = (lg & 1) ? a[3] : a[2];
  return (lg & 2) ? v23 : v01;
}

// ---------------- Layer 1 (R3-proven, verbatim) ----------------
__global__ __launch_bounds__(512) void lstm_layer1_kernel(
    const float* __restrict__ x,        // [1024,512,19]
    const float* __restrict__ Wih,      // [512,19]
    const float* __restrict__ Whh,      // [512,128]
    const float* __restrict__ bih, const float* __restrict__ bhh,
    _Float16* __restrict__ h1g)         // [512][1024][128] fp16 (T-major)
{
  __shared__ _Float16 xls[512][12][8];
  __shared__ _Float16 hbuf[2][64][8];
  const int tid = threadIdx.x, bid = blockIdx.x;
  const int wv = tid >> 6, lane = tid & 63;
  const int lg = lane >> 4, lc = lane & 15;
  const int col = wv * 16 + lc;
  const int off0 = lg * 32 + (lc & 3) * 8;
  const int woff = ((wv * 2 + (lc >> 3)) * 4 + lg) * 8 + (lc & 7);

  half8 wih_f[4], whh_f[4][4];
  float bias[4];
#pragma unroll
  for (int g = 0; g < 4; ++g) {
    const int n = g * 128 + col;
    bias[g] = bih[n] + bhh[n];
    half8 f;
#pragma unroll
    for (int j = 0; j < 8; ++j) {
      const int k = lg * 8 + j;
      f[j] = (_Float16)((k < 19) ? Wih[n * 19 + k] : 0.f);
    }
    wih_f[g] = f;
#pragma unroll
    for (int kk = 0; kk < 4; ++kk) {
      const float* p = Whh + n * 128 + kk * 32 + lg * 8;
      half8 f2;
#pragma unroll
      for (int j = 0; j < 8; ++j) f2[j] = (_Float16)p[j];
      whh_f[g][kk] = f2;
    }
  }

  for (int i2 = tid; i2 < 512 * 96; i2 += 512) {
    const int t = i2 / 96, r = i2 - t * 96;
    const int cc = r >> 5, rr = (r >> 3) & 3, j = r & 7;
    const int k = cc * 8 + j;
    float v = 0.f;
    if (k < 19) v = x[((size_t)(bid * 4 + rr) * 512 + t) * 19 + k];
    xls[t][cc * 4 + rr][j] = (_Float16)v;
  }
  for (int i = tid; i < 1024; i += 512) ((_Float16*)hbuf)[i] = (_Float16)0.f;
  __syncthreads();

  float c = 0.f;
  _Float16* h1p = h1g + (size_t)(bid * 4 + lg) * 128 + col;
  const _Float16* xb = &xls[0][0][0] + off0;
  _Float16* hb0p = &hbuf[0][0][0];
  const f32x4 fz = {0.f, 0.f, 0.f, 0.f};
  const bool xv = (lg < 3);

#define L1_STEP(T, RD, WR)                                                    \
  {                                                                           \
    const _Float16* rd = (RD) + off0;                                         \
    const half8 hb0 = *(const half8*)(rd);                                    \
    const half8 hb1 = *(const half8*)(rd + 128);                              \
    const half8 hb2 = *(const half8*)(rd + 256);                              \
    const half8 hb3 = *(const half8*)(rd + 384);                              \
    half8 ax = {};                                                            \
    if (xv) ax = *(const half8*)(xb + (T) * 96);                              \
    f32x4 a0 = MFMA16(ax, wih_f[0], fz);                                      \
    f32x4 a1 = MFMA16(ax, wih_f[1], fz);                                      \
    f32x4 a2 = MFMA16(ax, wih_f[2], fz);                                      \
    f32x4 a3 = MFMA16(ax, wih_f[3], fz);                                      \
    a0 = MFMA16(hb0, whh_f[0][0], a0); a1 = MFMA16(hb0, whh_f[1][0], a1);     \
    a2 = MFMA16(hb0, whh_f[2][0], a2); a3 = MFMA16(hb0, whh_f[3][0], a3);     \
    a0 = MFMA16(hb1, whh_f[0][1], a0); a1 = MFMA16(hb1, whh_f[1][1], a1);     \
    a2 = MFMA16(hb1, whh_f[2][1], a2); a3 = MFMA16(hb1, whh_f[3][1], a3);     \
    a0 = MFMA16(hb2, whh_f[0][2], a0); a1 = MFMA16(hb2, whh_f[1][2], a1);     \
    a2 = MFMA16(hb2, whh_f[2][2], a2); a3 = MFMA16(hb2, whh_f[3][2], a3);     \
    a0 = MFMA16(hb3, whh_f[0][3], a0); a1 = MFMA16(hb3, whh_f[1][3], a1);     \
    a2 = MFMA16(hb3, whh_f[2][3], a2); a3 = MFMA16(hb3, whh_f[3][3], a3);     \
    const float gi = sel4(a0, lg) + bias[0];                                  \
    const float gf = sel4(a1, lg) + bias[1];                                  \
    const float gg = sel4(a2, lg) + bias[2];                                  \
    const float go = sel4(a3, lg) + bias[3];                                  \
    const float I = sigf(gi), F = sigf(gf), G = tanhf_(gg), O = sigf(go);     \
    c = F * c + I * G;                                                        \
    const float h = O * tanhf_(c);                                            \
    const _Float16 h16 = (_Float16)h;                                         \
    (WR)[woff] = h16;                                                         \
    h1p[(size_t)(T) * 131072] = h16;                                          \
    BARRIER();                                                                \
  }

#pragma unroll 1
  for (int t = 0; t < 512; t += 2) {
    L1_STEP(t, hb0p + 512, hb0p);
    L1_STEP(t + 1, hb0p, hb0p + 512);
  }
#undef L1_STEP
}

// -------- L2 pre-GEMM: P[tl][bid][g][col][r4] fp16 = bias2 + h1(t)@Wih2^T --------
__global__ __launch_bounds__(512) void lstm2_pre_kernel(
    const _Float16* __restrict__ h1g,   // [512][1024][128]
    const float* __restrict__ Wih,      // [512,128]
    const float* __restrict__ bih, const float* __restrict__ bhh,
    _Float16* __restrict__ pre, int t0, int Tc)
{
  const int tid = threadIdx.x, bid = blockIdx.x;
  const int wv = tid >> 6, lane = tid & 63;
  const int lg = lane >> 4, lc = lane & 15;
  const int col = wv * 16 + lc;

  half8 wi_f[4][4];
  f32x4 bV[4];
#pragma unroll
  for (int g = 0; g < 4; ++g) {
    const int n = g * 128 + col;
    const float bb = bih[n] + bhh[n];
    f32x4 bv = {bb, bb, bb, bb};
    bV[g] = bv;
#pragma unroll
    for (int kk = 0; kk < 4; ++kk) {
      const float* p = Wih + n * 128 + kk * 32 + lg * 8;
      half8 f;
#pragma unroll
      for (int j = 0; j < 8; ++j) f[j] = (_Float16)p[j];
      wi_f[g][kk] = f;
    }
    pin(wi_f[g][0]); pin(wi_f[g][1]); pin(wi_f[g][2]); pin(wi_f[g][3]);
    pinf(bV[g]);
  }

  const _Float16* h1p = h1g + ((size_t)t0 * 1024 + bid * 4 + (lc & 3)) * 128 + lg * 8;
  _Float16* pp = pre + (size_t)bid * 2048 + (size_t)(col << 2);
  const bool wr = (lg == 0);

#pragma unroll 1
  for (int tl = 0; tl < Tc; ++tl) {
    const _Float16* hp = h1p + (size_t)tl * 131072;
    const half8 a0 = *(const half8*)(hp);
    const half8 a1 = *(const half8*)(hp + 32);
    const half8 a2 = *(const half8*)(hp + 64);
    const half8 a3 = *(const half8*)(hp + 96);
    f32x4 c0 = bV[0], c1 = bV[1], c2 = bV[2], c3 = bV[3];
    c0 = MFMA16(a0, wi_f[0][0], c0); c1 = MFMA16(a0, wi_f[1][0], c1);
    c2 = MFMA16(a0, wi_f[2][0], c2); c3 = MFMA16(a0, wi_f[3][0], c3);
    c0 = MFMA16(a1, wi_f[0][1], c0); c1 = MFMA16(a1, wi_f[1][1], c1);
    c2 = MFMA16(a1, wi_f[2][1], c2); c3 = MFMA16(a1, wi_f[3][1], c3);
    c0 = MFMA16(a2, wi_f[0][2], c0); c1 = MFMA16(a2, wi_f[1][2], c1);
    c2 = MFMA16(a2, wi_f[2][2], c2); c3 = MFMA16(a2, wi_f[3][2], c3);
    c0 = MFMA16(a3, wi_f[0][3], c0); c1 = MFMA16(a3, wi_f[1][3], c1);
    c2 = MFMA16(a3, wi_f[2][3], c2); c3 = MFMA16(a3, wi_f[3][3], c3);
    if (wr) {
      _Float16* pw = pp + (size_t)tl * 524288;
      half4 h0, h1, h2, h3;
#pragma unroll
      for (int j = 0; j < 4; ++j) {
        h0[j] = (_Float16)c0[j]; h1[j] = (_Float16)c1[j];
        h2[j] = (_Float16)c2[j]; h3[j] = (_Float16)c3[j];
      }
      *(half4*)(pw + 0)    = h0;
      *(half4*)(pw + 512)  = h1;
      *(half4*)(pw + 1024) = h2;
      *(half4*)(pw + 1536) = h3;
    }
  }
}

// -------- L2 recurrence: wh2 only (spill-free), P streamed from HBM --------
__global__ __launch_bounds__(512) void lstm2_rec_kernel(
    const _Float16* __restrict__ pre,   // [Tc][256][4][128][4] fp16
    const float* __restrict__ Whh,      // [512,128]
    const float* __restrict__ Wlin,     // [7,128]
    const float* __restrict__ blin,     // [7]
    float* __restrict__ cstate,         // [1024*128] f32
    _Float16* __restrict__ hstate,      // [1024*128] fp16
    float* __restrict__ out,            // [1024, 3584]
    int t0, int Tc)
{
  __shared__ _Float16 h2b[2][512];
  __shared__ _Float16 wlls[16][132];
  const int tid = threadIdx.x, bid = blockIdx.x;
  const int wv = tid >> 6, lane = tid & 63;
  const int lg = lane >> 4, lc = lane & 15;
  const int col = wv * 16 + lc;
  const int off0 = lg * 32 + (lc & 3) * 8;
  const int woff = ((col >> 3) * 4 + lg) * 8 + (col & 7);

  half8 wh_f[4][4];
#pragma unroll
  for (int g = 0; g < 4; ++g) {
    const int n = g * 128 + col;
#pragma unroll
    for (int kk = 0; kk < 4; ++kk) {
      const float* p = Whh + n * 128 + kk * 32 + lg * 8;
      half8 f;
#pragma unroll
      for (int j = 0; j < 8; ++j) f[j] = (_Float16)p[j];
      wh_f[g][kk] = f;
    }
    pin(wh_f[g][0]); pin(wh_f[g][1]); pin(wh_f[g][2]); pin(wh_f[g][3]);
  }
  const bool yv = (lc < 7);
  const float ybias = yv ? blin[lc] : 0.f;
  const f32x4 ybV = {ybias, ybias, ybias, ybias};

  for (int i = tid; i < 16 * 128; i += 512)
    wlls[i >> 7][i & 127] = (_Float16)((i < 7 * 128) ? Wlin[i] : 0.f);

  const int sidx = (bid * 4 + lg) * 128 + col;
  float c;
  if (t0 == 0) {
    c = 0.f;
    for (int i = tid; i < 1024; i += 512) ((_Float16*)h2b)[i] = (_Float16)0.f;
  } else {
    c = cstate[sidx];
    h2b[(t0 & 1) ^ 1][woff] = hstate[sidx];   // h2(t0-1), parity (t0-1)&1
  }
  __syncthreads();

  const _Float16* pb_ = pre + (size_t)bid * 2048 + (size_t)(col << 2);
  half4 Pc0 = *(const half4*)(pb_ + 0);
  half4 Pc1 = *(const half4*)(pb_ + 512);
  half4 Pc2 = *(const half4*)(pb_ + 1024);
  half4 Pc3 = *(const half4*)(pb_ + 1536);
  float hlast = 0.f;

#pragma unroll 1
  for (int tl = 0; tl < Tc; ++tl) {
    const int t = t0 + tl;
    const int pb = t & 1;
    const _Float16* rd = &h2b[pb ^ 1][0] + off0;
    const half8 q0 = *(const half8*)(rd);
    const half8 q1 = *(const half8*)(rd + 128);
    const half8 q2 = *(const half8*)(rd + 256);
    const half8 q3 = *(const half8*)(rd + 384);
    // prefetch next step's P (stream, off-chain)
    const size_t tn = (size_t)((tl + 1 < Tc) ? tl + 1 : tl) * 524288;
    const half4 Pn0 = *(const half4*)(pb_ + tn + 0);
    const half4 Pn1 = *(const half4*)(pb_ + tn + 512);
    const half4 Pn2 = *(const half4*)(pb_ + tn + 1024);
    const half4 Pn3 = *(const half4*)(pb_ + tn + 1536);

    f32x4 a0 = {(float)Pc0[0], (float)Pc0[1], (float)Pc0[2], (float)Pc0[3]};
    f32x4 a1 = {(float)Pc1[0], (float)Pc1[1], (float)Pc1[2], (float)Pc1[3]};
    f32x4 a2 = {(float)Pc2[0], (float)Pc2[1], (float)Pc2[2], (float)Pc2[3]};
    f32x4 a3 = {(float)Pc3[0], (float)Pc3[1], (float)Pc3[2], (float)Pc3[3]};
    a0 = MFMA16(q0, wh_f[0][0], a0); a1 = MFMA16(q0, wh_f[1][0], a1);
    a2 = MFMA16(q0, wh_f[2][0], a2); a3 = MFMA16(q0, wh_f[3][0], a3);
    a0 = MFMA16(q1, wh_f[0][1], a0); a1 = MFMA16(q1, wh_f[1][1], a1);
    a2 = MFMA16(q1, wh_f[2][1], a2); a3 = MFMA16(q1, wh_f[3][1], a3);
    a0 = MFMA16(q2, wh_f[0][2], a0); a1 = MFMA16(q2, wh_f[1][2], a1);
    a2 = MFMA16(q2, wh_f[2][2], a2); a3 = MFMA16(q2, wh_f[3][2], a3);
    a0 = MFMA16(q3, wh_f[0][3], a0); a1 = MFMA16(q3, wh_f[1][3], a1);
    a2 = MFMA16(q3, wh_f[2][3], a2); a3 = MFMA16(q3, wh_f[3][3], a3);

    const float gi = sel4(a0, lg), gf = sel4(a1, lg);
    const float gg = sel4(a2, lg), go = sel4(a3, lg);
    const float I = sigf(gi), F = sigf(gf), G = tanhf_(gg), O = sigf(go);
    c = F * c + I * G;
    const float h = O * tanhf_(c);
    hlast = h;
    h2b[pb][woff] = (_Float16)h;

    // y(t-1) from q = h2(t-1); wave 0 only; Wlin from LDS in pairs
    if (wv == 0 && t > 0) {
      const _Float16* wlp = &wlls[lc][0] + lg * 8;
      const half8 w0 = *(const half8*)(wlp);
      const half8 w1 = *(const half8*)(wlp + 32);
      f32x4 ya = ybV;
      ya = MFMA16(q0, w0, ya);
      ya = MFMA16(q1, w1, ya);
      const half8 w2 = *(const half8*)(wlp + 64);
      const half8 w3 = *(const half8*)(wlp + 96);
      ya = MFMA16(q2, w2, ya);
      ya = MFMA16(q3, w3, ya);
      if (lg == 0 && yv) {
#pragma unroll
        for (int j = 0; j < 4; ++j)
          out[(size_t)(bid * 4 + j) * 3584 + (size_t)(t - 1) * 7 + lc] = ya[j];
      }
    }
    Pc0 = Pn0; Pc1 = Pn1; Pc2 = Pn2; Pc3 = Pn3;
    BARRIER();
  }

  cstate[sidx] = c;
  hstate[sidx] = (_Float16)hlast;

  if (t0 + Tc == 512 && wv == 0) {     // final y(511): h2(511) in h2b[1]
    const _Float16* rd = &h2b[1][0] + off0;
    const half8 q0 = *(const half8*)(rd);
    const half8 q1 = *(const half8*)(rd + 128);
    const half8 q2 = *(const half8*)(rd + 256);
    const half8 q3 = *(const half8*)(rd + 384);
    const _Float16* wlp = &wlls[lc][0] + lg * 8;
    const half8 w0 = *(const half8*)(wlp);
    const half8 w1 = *(const half8*)(wlp + 32);
    const half8 w2 = *(const half8*)(wlp + 64);
    const half8 w3 = *(const half8*)(wlp + 96);
    f32x4 ya = ybV;
    ya = MFMA16(q0, w0, ya);
    ya = MFMA16(q1, w1, ya);
    ya = MFMA16(q2, w2, ya);
    ya = MFMA16(q3, w3, ya);
    if (lg == 0 && yv) {
#pragma unroll
      for (int j = 0; j < 4; ++j)
        out[(size_t)(bid * 4 + j) * 3584 + (size_t)511 * 7 + lc] = ya[j];
    }
  }
}

// -------- Fallback L2 (R7-proven, wi+wh in regs) if ws too small --------
__global__ __attribute__((amdgpu_waves_per_eu(2, 2))) __launch_bounds__(512)
void lstm_layer2_fallback(
    const _Float16* __restrict__ h1g, const float* __restrict__ Wih,
    const float* __restrict__ Whh, const float* __restrict__ bih,
    const float* __restrict__ bhh, const float* __restrict__ Wlin,
    const float* __restrict__ blin, float* __restrict__ out)
{
  __shared__ _Float16 hbuf[2][512];
  __shared__ _Float16 wlls[16][132];
  const int tid = threadIdx.x, bid = blockIdx.x;
  const int wv = tid >> 6, lane = tid & 63;
  const int lg = lane >> 4, lc = lane & 15;
  const int col = wv * 16 + lc;
  const int off0 = lg * 32 + (lc & 3) * 8;
  const int woff = ((col >> 3) * 4 + lg) * 8 + (col & 7);

  half8 wi_f[4][4], wh_f[4][4];
  float bias_s[4];
#pragma unroll
  for (int g = 0; g < 4; ++g) {
    const int n = g * 128 + col;
    bias_s[g] = bih[n] + bhh[n];
#pragma unroll
    for (int kk = 0; kk < 4; ++kk) {
      const float* pi = Wih + n * 128 + kk * 32 + lg * 8;
      const float* ph = Whh + n * 128 + kk * 32 + lg * 8;
      half8 fi, fh;
#pragma unroll
      for (int j = 0; j < 8; ++j) { fi[j] = (_Float16)pi[j]; fh[j] = (_Float16)ph[j]; }
      wi_f[g][kk] = fi;
      wh_f[g][kk] = fh;
    }
    pin(wi_f[g][0]); pin(wi_f[g][1]); pin(wi_f[g][2]); pin(wi_f[g][3]);
    pin(wh_f[g][0]); pin(wh_f[g][1]); pin(wh_f[g][2]); pin(wh_f[g][3]);
  }
  const f32x4 bV0 = {bias_s[0], bias_s[0], bias_s[0], bias_s[0]};
  const f32x4 bV1 = {bias_s[1], bias_s[1], bias_s[1], bias_s[1]};
  const f32x4 bV2 = {bias_s[2], bias_s[2], bias_s[2], bias_s[2]};
  const f32x4 bV3 = {bias_s[3], bias_s[3], bias_s[3], bias_s[3]};
  const bool yv = (lc < 7);
  const float ybias = yv ? blin[lc] : 0.f;
  const f32x4 ybV = {ybias, ybias, ybias, ybias};

  for (int i = tid; i < 16 * 128; i += 512)
    wlls[i >> 7][i & 127] = (_Float16)((i < 7 * 128) ? Wlin[i] : 0.f);
  for (int i = tid; i < 1024; i += 512) ((_Float16*)hbuf)[i] = (_Float16)0.f;
  __syncthreads();

  float c = 0.f;
  const _Float16* h1p = h1g + (size_t)(bid * 4 + (lc & 3)) * 128 + lg * 8;
  const f32x4 fz = {0.f, 0.f, 0.f, 0.f};
  half8 iC0 = *(const half8*)(h1p), iC1 = *(const half8*)(h1p + 32);
  half8 iC2 = *(const half8*)(h1p + 64), iC3 = *(const half8*)(h1p + 96);

#pragma unroll 1
  for (int t = 0; t < 512; ++t) {
    const int pb = t & 1;
    const _Float16* rd = &hbuf[pb ^ 1][0] + off0;
    const half8 hb0 = *(const half8*)(rd);
    const half8 hb1 = *(const half8*)(rd + 128);
    const half8 hb2 = *(const half8*)(rd + 256);
    const half8 hb3 = *(const half8*)(rd + 384);
    const size_t tn = (size_t)((t + 1 < 512) ? t + 1 : t) * 131072;
    const half8 iN0 = *(const half8*)(h1p + tn);
    const half8 iN1 = *(const half8*)(h1p + tn + 32);
    const half8 iN2 = *(const half8*)(h1p + tn + 64);
    const half8 iN3 = *(const half8*)(h1p + tn + 96);
    f32x4 a0 = MFMA16(iC0, wi_f[0][0], bV0);
    f32x4 a1 = MFMA16(iC0, wi_f[1][0], bV1);
    f32x4 a2 = MFMA16(iC0, wi_f[2][0], bV2);
    f32x4 a3 = MFMA16(iC0, wi_f[3][0], bV3);
    f32x4 b0 = MFMA16(hb0, wh_f[0][0], fz);
    f32x4 b1 = MFMA16(hb0, wh_f[1][0], fz);
    f32x4 b2 = MFMA16(hb0, wh_f[2][0], fz);
    f32x4 b3 = MFMA16(hb0, wh_f[3][0], fz);
    a0 = MFMA16(iC1, wi_f[0][1], a0); a1 = MFMA16(iC1, wi_f[1][1], a1);
    a2 = MFMA16(iC1, wi_f[2][1], a2); a3 = MFMA16(iC1, wi_f[3][1], a3);
    b0 = MFMA16(hb1, wh_f[0][1], b0); b1 = MFMA16(hb1, wh_f[1][1], b1);
    b2 = MFMA16(hb1, wh_f[2][1], b2); b3 = MFMA16(hb1, wh_f[3][1], b3);
    a0 = MFMA16(iC2, wi_f[0][2], a0); a1 = MFMA16(iC2, wi_f[1][2], a1);
    a2 = MFMA16(iC2, wi_f[2][2], a2); a3 = MFMA16(iC2, wi_f[3][2], a3);
    b0 = MFMA16(hb2, wh_f[0][2], b0); b1 = MFMA16(hb2, wh_f[1][2], b1);
    b2 = MFMA16(hb2, wh_f[2][2], b2); b3 = MFMA16(hb2, wh_f[3][2], b3);
    a0 = MFMA16(iC3, wi_f[0][3], a0); a1 = MFMA16(iC3, wi_f[1][3], a1);
    a2 = MFMA16(iC3, wi_f[2][3], a2); a3 = MFMA16(iC3, wi_f[3][3], a3);
    b0 = MFMA16(hb3, wh_f[0][3], b0); b1 = MFMA16(hb3, wh_f[1][3], b1);
    b2 = MFMA16(hb3, wh_f[2][3], b2); b3 = MFMA16(hb3, wh_f[3][3], b3);
    if (wv == 0 && t > 0) {
      const _Float16* wlp = &wlls[lc][0] + lg * 8;
      const half8 w0 = *(const half8*)(wlp);
      const half8 w1 = *(const half8*)(wlp + 32);
      const half8 w2 = *(const half8*)(wlp + 64);
      const half8 w3 = *(const half8*)(wlp + 96);
      f32x4 ya = ybV;
      ya = MFMA16(hb0, w0, ya);
      ya = MFMA16(hb1, w1, ya);
      ya = MFMA16(hb2, w2, ya);
      ya = MFMA16(hb3, w3, ya);
      if (lg == 0 && yv) {
#pragma unroll
        for (int j = 0; j < 4; ++j)
          out[(size_t)(bid * 4 + j) * 3584 + (size_t)(t - 1) * 7 + lc] = ya[j];
      }
    }
    const f32x4 s0 = a0 + b0, s1 = a1 + b1, s2 = a2 + b2, s3 = a3 + b3;
    const float gi = sel4(s0, lg), gf = sel4(s1, lg);
    const float gg = sel4(s2, lg), go = sel4(s3, lg);
    const float I = sigf(gi), F = sigf(gf), G = tanhf_(gg), O = sigf(go);
    c = F * c + I * G;
    hbuf[pb][woff] = (_Float16)(O * tanhf_(c));
    iC0 = iN0; iC1 = iN1; iC2 = iN2; iC3 = iN3;
    BARRIER();
  }

  if (wv == 0) {
    const _Float16* rd = &hbuf[1][0] + off0;
    const half8 hb0 = *(const half8*)(rd);
    const half8 hb1 = *(const half8*)(rd + 128);
    const half8 hb2 = *(const half8*)(rd + 256);
    const half8 hb3 = *(const half8*)(rd + 384);
    const _Float16* wlp = &wlls[lc][0] + lg * 8;
    const half8 w0 = *(const half8*)(wlp);
    const half8 w1 = *(const half8*)(wlp + 32);
    const half8 w2 = *(const half8*)(wlp + 64);
    const half8 w3 = *(const half8*)(wlp + 96);
    f32x4 ya = ybV;
    ya = MFMA16(hb0, w0, ya);
    ya = MFMA16(hb1, w1, ya);
    ya = MFMA16(hb2, w2, ya);
    ya = MFMA16(hb3, w3, ya);
    if (lg == 0 && yv) {
#pragma unroll
      for (int j = 0; j < 4; ++j)
        out[(size_t)(bid * 4 + j) * 3584 + (size_t)511 * 7 + lc] = ya[j];
    }
  }
}

extern "C" void kernel_launch(void* const* d_in, const int* in_sizes, int n_in,
                              void* d_out, int out_size, void* d_ws, size_t ws_size,
                              hipStream_t stream) {
  (void)in_sizes; (void)n_in; (void)out_size;
  const float* x     = (const float*)d_in[0];
  const float* W_ih1 = (const float*)d_in[1];
  const float* W_hh1 = (const float*)d_in[2];
  const float* b_ih1 = (const float*)d_in[3];
  const float* b_hh1 = (const float*)d_in[4];
  const float* W_ih2 = (const float*)d_in[5];
  const float* W_hh2 = (const float*)d_in[6];
  const float* b_ih2 = (const float*)d_in[7];
  const float* b_hh2 = (const float*)d_in[8];
  const float* W_lin = (const float*)d_in[9];
  const float* b_lin = (const float*)d_in[10];
  float* out = (float*)d_out;

  char* ws = (char*)d_ws;
  const size_t h1_bytes = 134217728ull;            // [512][1024][128] fp16
  _Float16* h1g = (_Float16*)ws;
  float* cstate = (float*)(ws + h1_bytes);         // 512 KB
  _Float16* hstate = (_Float16*)(ws + h1_bytes + 524288);  // 256 KB
  const size_t pre_off = h1_bytes + 1048576;       // 1 MB state+pad
  _Float16* pre = (_Float16*)(ws + pre_off);

  int Tc = 0;
  for (int cand = 512; cand >= 64; cand >>= 1) {
    if (ws_size >= pre_off + (size_t)cand * 1048576ull) { Tc = cand; break; }
  }

  lstm_layer1_kernel<<<256, 512, 0, stream>>>(x, W_ih1, W_hh1, b_ih1, b_hh1, h1g);
  if (Tc > 0) {
    for (int t0 = 0; t0 < 512; t0 += Tc) {
      lstm2_pre_kernel<<<256, 512, 0, stream>>>(h1g, W_ih2, b_ih2, b_hh2, pre, t0, Tc);
      lstm2_rec_kernel<<<256, 512, 0, stream>>>(pre, W_hh2, W_lin, b_lin,
                                                cstate, hstate, out, t0, Tc);
    }
  } else {
    lstm_layer2_fallback<<<256, 512, 0, stream>>>(h1g, W_ih2, W_hh2, b_ih2, b_hh2,
                                                  W_lin, b_lin, out);
  }
}

// Round 11
// 815.882 us; speedup vs baseline: 1.9679x; 1.5551x over previous
//
#include <hip/hip_runtime.h>

// LSTMPredictor: B=1024, T=512, IN=19, H=128, OUT=7 (fp32 in/out)
// RECOMBINATION of best-proven halves, minimal 2-kernel module:
//  L1: R3-proven kernel verbatim (265 us in the R4 2-kernel module).
//  L2: R7-proven kernel verbatim (~470 us): waves_per_eu(2,2), wi2+wh2
//      pinned (unified VGPR/AGPR file absorbs the 128 weight regs),
//      two parallel depth-4 MFMA chains (wi||wh), Wlin in LDS, y on wave 0.
// D-layout row-dup invariant (R3): A-frag rows dup mod 4 -> acc_g[r] at every
// lane holds D_g[r][col]; lane (lg,lc) selects its own reg lg (sel4).

typedef _Float16 half8 __attribute__((ext_vector_type(8)));
typedef float f32x4 __attribute__((ext_vector_type(4)));

#define MFMA16(a, b, c) __builtin_amdgcn_mfma_f32_16x16x32_f16((a), (b), (c), 0, 0, 0)
#define BARRIER() asm volatile("s_waitcnt lgkmcnt(0)\ns_barrier" ::: "memory")

__device__ __forceinline__ void pin(half8& v) { asm volatile("" : "+v"(v)); }

__device__ __forceinline__ float sigf(float x) {
  return __builtin_amdgcn_rcpf(1.f + __expf(-x));   // NaN-free at +/-inf
}
__device__ __forceinline__ float tanhf_(float x) {
  return 1.f - 2.f * __builtin_amdgcn_rcpf(1.f + __expf(2.f * x));  // NaN-free
}
// acc_g[r] == D_g[r][lc] at every lane (duplication invariant) -> pick reg lg.
__device__ __forceinline__ float sel4(const f32x4 a, const int lg) {
  const float v01 = (lg & 1) ? a[1] : a[0];
  const float v23 = (lg & 1) ? a[3] : a[2];
  return (lg & 2) ? v23 : v01;
}

// ---------------- Layer 1 (R3-proven, verbatim) ----------------
__global__ __launch_bounds__(512) void lstm_layer1_kernel(
    const float* __restrict__ x,        // [1024,512,19]
    const float* __restrict__ Wih,      // [512,19]
    const float* __restrict__ Whh,      // [512,128]
    const float* __restrict__ bih, const float* __restrict__ bhh,
    _Float16* __restrict__ h1g)         // [512][1024][128] fp16 (T-major)
{
  __shared__ _Float16 xls[512][12][8];  // 98,304 B: fp16 x A-frags (k padded to 24)
  __shared__ _Float16 hbuf[2][64][8];   // 2 KiB
  const int tid = threadIdx.x, bid = blockIdx.x;
  const int wv = tid >> 6, lane = tid & 63;
  const int lg = lane >> 4, lc = lane & 15;
  const int col = wv * 16 + lc;
  const int off0 = lg * 32 + (lc & 3) * 8;
  const int woff = ((wv * 2 + (lc >> 3)) * 4 + lg) * 8 + (lc & 7);

  half8 wih_f[4], whh_f[4][4];
  float bias[4];
#pragma unroll
  for (int g = 0; g < 4; ++g) {
    const int n = g * 128 + col;
    bias[g] = bih[n] + bhh[n];
    half8 f;
#pragma unroll
    for (int j = 0; j < 8; ++j) {
      const int k = lg * 8 + j;
      f[j] = (_Float16)((k < 19) ? Wih[n * 19 + k] : 0.f);
    }
    wih_f[g] = f;
#pragma unroll
    for (int kk = 0; kk < 4; ++kk) {
      const float* p = Whh + n * 128 + kk * 32 + lg * 8;
      half8 f2;
#pragma unroll
      for (int j = 0; j < 8; ++j) f2[j] = (_Float16)p[j];
      whh_f[g][kk] = f2;
    }
  }

  for (int i2 = tid; i2 < 512 * 96; i2 += 512) {
    const int t = i2 / 96, r = i2 - t * 96;
    const int cc = r >> 5, rr = (r >> 3) & 3, j = r & 7;
    const int k = cc * 8 + j;
    float v = 0.f;
    if (k < 19) v = x[((size_t)(bid * 4 + rr) * 512 + t) * 19 + k];
    xls[t][cc * 4 + rr][j] = (_Float16)v;
  }
  for (int i = tid; i < 1024; i += 512) ((_Float16*)hbuf)[i] = (_Float16)0.f;
  __syncthreads();

  float c = 0.f;
  _Float16* h1p = h1g + (size_t)(bid * 4 + lg) * 128 + col;
  const _Float16* xb = &xls[0][0][0] + off0;
  _Float16* hb0p = &hbuf[0][0][0];
  const f32x4 fz = {0.f, 0.f, 0.f, 0.f};
  const bool xv = (lg < 3);

#define L1_STEP(T, RD, WR)                                                    \
  {                                                                           \
    const _Float16* rd = (RD) + off0;                                         \
    const half8 hb0 = *(const half8*)(rd);                                    \
    const half8 hb1 = *(const half8*)(rd + 128);                              \
    const half8 hb2 = *(const half8*)(rd + 256);                              \
    const half8 hb3 = *(const half8*)(rd + 384);                              \
    half8 ax = {};                                                            \
    if (xv) ax = *(const half8*)(xb + (T) * 96);                              \
    f32x4 a0 = MFMA16(ax, wih_f[0], fz);                                      \
    f32x4 a1 = MFMA16(ax, wih_f[1], fz);                                      \
    f32x4 a2 = MFMA16(ax, wih_f[2], fz);                                      \
    f32x4 a3 = MFMA16(ax, wih_f[3], fz);                                      \
    a0 = MFMA16(hb0, whh_f[0][0], a0); a1 = MFMA16(hb0, whh_f[1][0], a1);     \
    a2 = MFMA16(hb0, whh_f[2][0], a2); a3 = MFMA16(hb0, whh_f[3][0], a3);     \
    a0 = MFMA16(hb1, whh_f[0][1], a0); a1 = MFMA16(hb1, whh_f[1][1], a1);     \
    a2 = MFMA16(hb1, whh_f[2][1], a2); a3 = MFMA16(hb1, whh_f[3][1], a3);     \
    a0 = MFMA16(hb2, whh_f[0][2], a0); a1 = MFMA16(hb2, whh_f[1][2], a1);     \
    a2 = MFMA16(hb2, whh_f[2][2], a2); a3 = MFMA16(hb2, whh_f[3][2], a3);     \
    a0 = MFMA16(hb3, whh_f[0][3], a0); a1 = MFMA16(hb3, whh_f[1][3], a1);     \
    a2 = MFMA16(hb3, whh_f[2][3], a2); a3 = MFMA16(hb3, whh_f[3][3], a3);     \
    const float gi = sel4(a0, lg) + bias[0];                                  \
    const float gf = sel4(a1, lg) + bias[1];                                  \
    const float gg = sel4(a2, lg) + bias[2];                                  \
    const float go = sel4(a3, lg) + bias[3];                                  \
    const float I = sigf(gi), F = sigf(gf), G = tanhf_(gg), O = sigf(go);     \
    c = F * c + I * G;                                                        \
    const float h = O * tanhf_(c);                                            \
    const _Float16 h16 = (_Float16)h;                                         \
    (WR)[woff] = h16;                                                         \
    h1p[(size_t)(T) * 131072] = h16;                                          \
    BARRIER();                                                                \
  }

#pragma unroll 1
  for (int t = 0; t < 512; t += 2) {
    L1_STEP(t, hb0p + 512, hb0p);
    L1_STEP(t + 1, hb0p, hb0p + 512);
  }
#undef L1_STEP
}

// ------- Layer 2 + Linear (R7-proven, verbatim): 256 blocks, 2 waves/EU -------
__global__ __attribute__((amdgpu_waves_per_eu(2, 2))) __launch_bounds__(512)
void lstm_layer2_kernel(
    const _Float16* __restrict__ h1g,   // [512][1024][128]
    const float* __restrict__ Wih,      // [512,128]
    const float* __restrict__ Whh,      // [512,128]
    const float* __restrict__ bih, const float* __restrict__ bhh,
    const float* __restrict__ Wlin,     // [7,128]
    const float* __restrict__ blin,     // [7]
    float* __restrict__ out)            // [1024, 3584]
{
  __shared__ _Float16 hbuf[2][512];     // 2 KiB
  __shared__ _Float16 wlls[16][136];    // Wlin staged (pad 136)
  const int tid = threadIdx.x, bid = blockIdx.x;
  const int wv = tid >> 6, lane = tid & 63;
  const int lg = lane >> 4, lc = lane & 15;
  const int col = wv * 16 + lc;
  const int off0 = lg * 32 + (lc & 3) * 8;
  const int woff = ((col >> 3) * 4 + lg) * 8 + (col & 7);

  half8 wi_f[4][4], wh_f[4][4];
  float bias_s[4];
#pragma unroll
  for (int g = 0; g < 4; ++g) {
    const int n = g * 128 + col;
    bias_s[g] = bih[n] + bhh[n];
#pragma unroll
    for (int kk = 0; kk < 4; ++kk) {
      const float* pi = Wih + n * 128 + kk * 32 + lg * 8;
      const float* ph = Whh + n * 128 + kk * 32 + lg * 8;
      half8 fi, fh;
#pragma unroll
      for (int j = 0; j < 8; ++j) { fi[j] = (_Float16)pi[j]; fh[j] = (_Float16)ph[j]; }
      wi_f[g][kk] = fi;
      wh_f[g][kk] = fh;
    }
    pin(wi_f[g][0]); pin(wi_f[g][1]); pin(wi_f[g][2]); pin(wi_f[g][3]);
    pin(wh_f[g][0]); pin(wh_f[g][1]); pin(wh_f[g][2]); pin(wh_f[g][3]);
  }
  const f32x4 bV0 = {bias_s[0], bias_s[0], bias_s[0], bias_s[0]};
  const f32x4 bV1 = {bias_s[1], bias_s[1], bias_s[1], bias_s[1]};
  const f32x4 bV2 = {bias_s[2], bias_s[2], bias_s[2], bias_s[2]};
  const f32x4 bV3 = {bias_s[3], bias_s[3], bias_s[3], bias_s[3]};
  const bool yv = (lc < 7);
  const float ybias = yv ? blin[lc] : 0.f;
  const f32x4 ybV = {ybias, ybias, ybias, ybias};

  for (int i = tid; i < 16 * 128; i += 512)
    wlls[i >> 7][i & 127] = (_Float16)((i < 7 * 128) ? Wlin[i] : 0.f);
  for (int i = tid; i < 1024; i += 512) ((_Float16*)hbuf)[i] = (_Float16)0.f;
  __syncthreads();

  float c = 0.f;
  const _Float16* h1p = h1g + (size_t)(bid * 4 + (lc & 3)) * 128 + lg * 8;
  const f32x4 fz = {0.f, 0.f, 0.f, 0.f};
  half8 iC0 = *(const half8*)(h1p), iC1 = *(const half8*)(h1p + 32);
  half8 iC2 = *(const half8*)(h1p + 64), iC3 = *(const half8*)(h1p + 96);

#pragma unroll 1
  for (int t = 0; t < 512; ++t) {
    const int pb = t & 1;
    const _Float16* rd = &hbuf[pb ^ 1][0] + off0;
    const half8 hb0 = *(const half8*)(rd);
    const half8 hb1 = *(const half8*)(rd + 128);
    const half8 hb2 = *(const half8*)(rd + 256);
    const half8 hb3 = *(const half8*)(rd + 384);
    const size_t tn = (size_t)((t + 1 < 512) ? t + 1 : t) * 131072;
    const half8 iN0 = *(const half8*)(h1p + tn);
    const half8 iN1 = *(const half8*)(h1p + tn + 32);
    const half8 iN2 = *(const half8*)(h1p + tn + 64);
    const half8 iN3 = *(const half8*)(h1p + tn + 96);
    // two parallel depth-4 chains: wi*h1 (regs, bias C-in) || wh*h2 (LDS)
    f32x4 a0 = MFMA16(iC0, wi_f[0][0], bV0);
    f32x4 a1 = MFMA16(iC0, wi_f[1][0], bV1);
    f32x4 a2 = MFMA16(iC0, wi_f[2][0], bV2);
    f32x4 a3 = MFMA16(iC0, wi_f[3][0], bV3);
    f32x4 b0 = MFMA16(hb0, wh_f[0][0], fz);
    f32x4 b1 = MFMA16(hb0, wh_f[1][0], fz);
    f32x4 b2 = MFMA16(hb0, wh_f[2][0], fz);
    f32x4 b3 = MFMA16(hb0, wh_f[3][0], fz);
    a0 = MFMA16(iC1, wi_f[0][1], a0); a1 = MFMA16(iC1, wi_f[1][1], a1);
    a2 = MFMA16(iC1, wi_f[2][1], a2); a3 = MFMA16(iC1, wi_f[3][1], a3);
    b0 = MFMA16(hb1, wh_f[0][1], b0); b1 = MFMA16(hb1, wh_f[1][1], b1);
    b2 = MFMA16(hb1, wh_f[2][1], b2); b3 = MFMA16(hb1, wh_f[3][1], b3);
    a0 = MFMA16(iC2, wi_f[0][2], a0); a1 = MFMA16(iC2, wi_f[1][2], a1);
    a2 = MFMA16(iC2, wi_f[2][2], a2); a3 = MFMA16(iC2, wi_f[3][2], a3);
    b0 = MFMA16(hb2, wh_f[0][2], b0); b1 = MFMA16(hb2, wh_f[1][2], b1);
    b2 = MFMA16(hb2, wh_f[2][2], b2); b3 = MFMA16(hb2, wh_f[3][2], b3);
    a0 = MFMA16(iC3, wi_f[0][3], a0); a1 = MFMA16(iC3, wi_f[1][3], a1);
    a2 = MFMA16(iC3, wi_f[2][3], a2); a3 = MFMA16(iC3, wi_f[3][3], a3);
    b0 = MFMA16(hb3, wh_f[0][3], b0); b1 = MFMA16(hb3, wh_f[1][3], b1);
    b2 = MFMA16(hb3, wh_f[2][3], b2); b3 = MFMA16(hb3, wh_f[3][3], b3);
    // y(t-1) from hb = h2(t-1); wave 0 only
    if (wv == 0 && t > 0) {
      const _Float16* wlp = &wlls[lc][0] + lg * 8;
      const half8 w0 = *(const half8*)(wlp);
      const half8 w1 = *(const half8*)(wlp + 32);
      const half8 w2 = *(const half8*)(wlp + 64);
      const half8 w3 = *(const half8*)(wlp + 96);
      f32x4 ya = ybV;
      ya = MFMA16(hb0, w0, ya);
      ya = MFMA16(hb1, w1, ya);
      ya = MFMA16(hb2, w2, ya);
      ya = MFMA16(hb3, w3, ya);
      if (lg == 0 && yv) {
#pragma unroll
        for (int j = 0; j < 4; ++j)
          out[(size_t)(bid * 4 + j) * 3584 + (size_t)(t - 1) * 7 + lc] = ya[j];
      }
    }
    const f32x4 s0 = a0 + b0, s1 = a1 + b1, s2 = a2 + b2, s3 = a3 + b3;
    const float gi = sel4(s0, lg), gf = sel4(s1, lg);
    const float gg = sel4(s2, lg), go = sel4(s3, lg);
    const float I = sigf(gi), F = sigf(gf), G = tanhf_(gg), O = sigf(go);
    c = F * c + I * G;
    hbuf[pb][woff] = (_Float16)(O * tanhf_(c));
    iC0 = iN0; iC1 = iN1; iC2 = iN2; iC3 = iN3;
    BARRIER();
  }

  // final y(511) from h2(511) in hbuf[1]
  if (wv == 0) {
    const _Float16* rd = &hbuf[1][0] + off0;
    const half8 hb0 = *(const half8*)(rd);
    const half8 hb1 = *(const half8*)(rd + 128);
    const half8 hb2 = *(const half8*)(rd + 256);
    const half8 hb3 = *(const half8*)(rd + 384);
    const _Float16* wlp = &wlls[lc][0] + lg * 8;
    const half8 w0 = *(const half8*)(wlp);
    const half8 w1 = *(const half8*)(wlp + 32);
    const half8 w2 = *(const half8*)(wlp + 64);
    const half8 w3 = *(const half8*)(wlp + 96);
    f32x4 ya = ybV;
    ya = MFMA16(hb0, w0, ya);
    ya = MFMA16(hb1, w1, ya);
    ya = MFMA16(hb2, w2, ya);
    ya = MFMA16(hb3, w3, ya);
    if (lg == 0 && yv) {
#pragma unroll
      for (int j = 0; j < 4; ++j)
        out[(size_t)(bid * 4 + j) * 3584 + (size_t)511 * 7 + lc] = ya[j];
    }
  }
}

extern "C" void kernel_launch(void* const* d_in, const int* in_sizes, int n_in,
                              void* d_out, int out_size, void* d_ws, size_t ws_size,
                              hipStream_t stream) {
  (void)in_sizes; (void)n_in; (void)out_size; (void)ws_size;
  const float* x     = (const float*)d_in[0];
  const float* W_ih1 = (const float*)d_in[1];
  const float* W_hh1 = (const float*)d_in[2];
  const float* b_ih1 = (const float*)d_in[3];
  const float* b_hh1 = (const float*)d_in[4];
  const float* W_ih2 = (const float*)d_in[5];
  const float* W_hh2 = (const float*)d_in[6];
  const float* b_ih2 = (const float*)d_in[7];
  const float* b_hh2 = (const float*)d_in[8];
  const float* W_lin = (const float*)d_in[9];
  const float* b_lin = (const float*)d_in[10];
  float* out = (float*)d_out;
  _Float16* h1g = (_Float16*)d_ws;   // [512][1024][128] fp16 = 134,217,728 bytes

  lstm_layer1_kernel<<<256, 512, 0, stream>>>(x, W_ih1, W_hh1, b_ih1, b_hh1, h1g);
  lstm_layer2_kernel<<<256, 512, 0, stream>>>(h1g, W_ih2, W_hh2, b_ih2, b_hh2,
                                              W_lin, b_lin, out);
}